// Round 5
// baseline (617.682 us; speedup 1.0000x reference)
//
#include <hip/hip_runtime.h>
#include <math.h>

#define N_NODES 50000
#define N_EDGES 1600000
#define IN_CH   512
#define OUT_CH  48
#define N_TILES (N_NODES / 16)       // 3125 row-tiles, exact

#define BSHIFT  6                    // 64 nodes per bucket
#define BNODES  64
#define NB      ((N_NODES + BNODES - 1) / BNODES)   // 782 buckets
#define ETILE   8192                 // edges per bin_edges block

typedef __attribute__((ext_vector_type(8))) short bf16x8;
typedef __attribute__((ext_vector_type(4))) float f32x4;

// fp32 -> bf16 (round-to-nearest-even), branch-free
static __device__ inline short f2bf(float x) {
    union { float f; unsigned u; } in; in.f = x;
    unsigned r = in.u + 0x7fffu + ((in.u >> 16) & 1u);
    return (short)(r >> 16);
}

// ---------------- Kernel 1: xw = features @ weight via bf16 MFMA ----------------
__global__ __launch_bounds__(256) void gemm_mfma(const float* __restrict__ f,
                                                 const float* __restrict__ w,
                                                 float* __restrict__ xw) {
    __shared__ bf16x8 sB[16 * 3 * 64];   // [s][t][lane], 48 KB

    int tid  = threadIdx.x;
    int lane = tid & 63;
    int wid  = tid >> 6;

    // stage B fragments: w[k][col] -> bf16, frag layout col=lane&15, k=8*(lane>>4)+j
    for (int idx = tid; idx < 16 * 3 * 64 * 8; idx += 256) {
        int j  = idx & 7;
        int ln = (idx >> 3) & 63;
        int st = idx >> 9;           // s*3 + t
        int t  = st % 3;
        int s  = st / 3;
        int k   = s * 32 + ((ln >> 4) << 3) + j;
        int col = t * 16 + (ln & 15);
        reinterpret_cast<short*>(sB)[idx] = f2bf(w[k * OUT_CH + col]);
    }
    __syncthreads();

    int tile = blockIdx.x * 4 + wid;
    if (tile >= N_TILES) return;

    int row = tile * 16 + (lane & 15);
    const float* fp = f + (size_t)row * IN_CH + ((lane >> 4) << 3);

    f32x4 acc0 = {0.f, 0.f, 0.f, 0.f};
    f32x4 acc1 = {0.f, 0.f, 0.f, 0.f};
    f32x4 acc2 = {0.f, 0.f, 0.f, 0.f};

    #pragma unroll 4
    for (int s = 0; s < 16; ++s) {
        float4 a0 = *reinterpret_cast<const float4*>(fp + s * 32);
        float4 a1 = *reinterpret_cast<const float4*>(fp + s * 32 + 4);
        bf16x8 a;
        a[0] = f2bf(a0.x); a[1] = f2bf(a0.y); a[2] = f2bf(a0.z); a[3] = f2bf(a0.w);
        a[4] = f2bf(a1.x); a[5] = f2bf(a1.y); a[6] = f2bf(a1.z); a[7] = f2bf(a1.w);
        bf16x8 b0 = sB[(s * 3 + 0) * 64 + lane];
        bf16x8 b1 = sB[(s * 3 + 1) * 64 + lane];
        bf16x8 b2 = sB[(s * 3 + 2) * 64 + lane];
        acc0 = __builtin_amdgcn_mfma_f32_16x16x32_bf16(a, b0, acc0, 0, 0, 0);
        acc1 = __builtin_amdgcn_mfma_f32_16x16x32_bf16(a, b1, acc1, 0, 0, 0);
        acc2 = __builtin_amdgcn_mfma_f32_16x16x32_bf16(a, b2, acc2, 0, 0, 0);
    }

    float* orow = xw + (size_t)tile * 16 * OUT_CH;
    int c  = lane & 15;
    int r0 = (lane >> 4) * 4;
    #pragma unroll
    for (int r = 0; r < 4; ++r) {
        orow[(size_t)(r0 + r) * OUT_CH +  0 + c] = acc0[r];
        orow[(size_t)(r0 + r) * OUT_CH + 16 + c] = acc1[r];
        orow[(size_t)(r0 + r) * OUT_CH + 32 + c] = acc2[r];
    }
}

// ---------------- Kernel 2: per-bucket histogram (LDS-staged) ----------------
__global__ __launch_bounds__(256) void bucket_hist(const int* __restrict__ dst,
                                                   int* __restrict__ counts) {
    __shared__ int h[NB];
    for (int i = threadIdx.x; i < NB; i += blockDim.x) h[i] = 0;
    __syncthreads();
    for (int e = blockIdx.x * blockDim.x + threadIdx.x; e < N_EDGES;
         e += gridDim.x * blockDim.x)
        atomicAdd(&h[dst[e] >> BSHIFT], 1);
    __syncthreads();
    for (int i = threadIdx.x; i < NB; i += blockDim.x)
        if (h[i]) atomicAdd(&counts[i], h[i]);
}

// ---------------- Kernel 3: exclusive scan over NB buckets (1 block) ----------------
__global__ __launch_bounds__(1024) void bucket_scan(const int* __restrict__ counts,
                                                    int* __restrict__ base,
                                                    int* __restrict__ cursor) {
    __shared__ int sdata[1024];
    int t = threadIdx.x;
    int v = (t < NB) ? counts[t] : 0;
    sdata[t] = v;
    __syncthreads();
    for (int d = 1; d < 1024; d <<= 1) {
        int x = (t >= d) ? sdata[t - d] : 0;
        __syncthreads();
        sdata[t] += x;
        __syncthreads();
    }
    if (t < NB) { int e = sdata[t] - v; base[t] = e; cursor[t] = e; }
}

// ---------------- Kernel 4: LDS-staged binning (coalesced scatter) ----------------
// Each block owns one tile of ETILE edges: local hist -> local scan -> bulk cursor
// reservation -> stage reordered tile in LDS -> stream out (runs of ~10 entries
// per bucket go to consecutive global slots).
__global__ __launch_bounds__(512) void bin_edges(const int* __restrict__ src,
                                                 const int* __restrict__ dst,
                                                 const float* __restrict__ ew,
                                                 int* __restrict__ cursor,
                                                 int2* __restrict__ epack) {
    __shared__ int   hist[NB];
    __shared__ int   loff[NB];
    __shared__ int   gbase[NB];
    __shared__ int   ssum[512];
    __shared__ int2  buf[ETILE];      // 64 KB
    __shared__ short bkt[ETILE];      // 16 KB

    int tid = threadIdx.x;
    int tileStart = blockIdx.x * ETILE;
    int tileN = N_EDGES - tileStart; if (tileN > ETILE) tileN = ETILE;

    for (int i = tid; i < NB; i += 512) hist[i] = 0;
    __syncthreads();

    // pass A: ranks via LDS histogram
    int rank[ETILE / 512];
    #pragma unroll
    for (int k = 0; k < ETILE / 512; ++k) {
        int e = tileStart + k * 512 + tid;
        rank[k] = (e < N_EDGES) ? atomicAdd(&hist[dst[e] >> BSHIFT], 1) : 0;
    }
    __syncthreads();

    // reserve global space per bucket
    for (int i = tid; i < NB; i += 512) {
        int c = hist[i];
        gbase[i] = c ? atomicAdd(&cursor[i], c) : 0;
    }

    // exclusive scan of hist -> loff (2 entries per thread)
    int a0 = (2 * tid     < NB) ? hist[2 * tid]     : 0;
    int a1 = (2 * tid + 1 < NB) ? hist[2 * tid + 1] : 0;
    ssum[tid] = a0 + a1;
    __syncthreads();
    for (int d = 1; d < 512; d <<= 1) {
        int x = (tid >= d) ? ssum[tid - d] : 0;
        __syncthreads();
        ssum[tid] += x;
        __syncthreads();
    }
    int excl = ssum[tid] - (a0 + a1);
    if (2 * tid     < NB) loff[2 * tid]     = excl;
    if (2 * tid + 1 < NB) loff[2 * tid + 1] = excl + a0;
    __syncthreads();

    // pass B: stage edges into LDS in bucket order
    #pragma unroll
    for (int k = 0; k < ETILE / 512; ++k) {
        int e = tileStart + k * 512 + tid;
        if (e < N_EDGES) {
            int d = dst[e];
            int b = d >> BSHIFT;
            int slot = loff[b] + rank[k];
            int2 p;
            p.x = src[e] | ((d & (BNODES - 1)) << 16);   // src fits 16 bits
            p.y = __float_as_int(ew[e]);
            buf[slot] = p;
            bkt[slot] = (short)b;
        }
    }
    __syncthreads();

    // streaming writeout: consecutive slots -> consecutive global positions
    for (int idx = tid; idx < tileN; idx += 512) {
        int b = bkt[idx];
        epack[gbase[b] + idx - loff[b]] = buf[idx];
    }
}

// ---------------- Kernel 5: per-bucket aggregate + bias + log-softmax ----------------
// One block per bucket: 64-node x 48-ch fp32 accumulator in LDS, ds_add_f32
// atomics, fused epilogue.
__global__ __launch_bounds__(256) void bucket_aggregate_lsm(
        const int* __restrict__ base, const int* __restrict__ cursor,
        const int2* __restrict__ epack, const float* __restrict__ xw,
        const float* __restrict__ bias, float* __restrict__ out) {
    __shared__ float acc[BNODES][OUT_CH];   // 12 KB

    int b = blockIdx.x;
    int tid = threadIdx.x, lane = tid & 63, wid = tid >> 6;

    for (int i = tid; i < BNODES * OUT_CH; i += 256)
        reinterpret_cast<float*>(acc)[i] = 0.f;
    __syncthreads();

    int lo = base[b], hi = cursor[b];
    int len = hi - lo;
    int per = (len + 3) >> 2;
    int myLo = lo + wid * per;
    int myHi = myLo + per; if (myHi > hi) myHi = hi;

    bool ch = (lane < OUT_CH);
    int i = myLo;
    for (; i + 3 < myHi; i += 4) {
        int2 p0 = epack[i], p1 = epack[i + 1], p2 = epack[i + 2], p3 = epack[i + 3];
        if (ch) {
            float x0 = xw[(size_t)(p0.x & 0xFFFF) * OUT_CH + lane];
            float x1 = xw[(size_t)(p1.x & 0xFFFF) * OUT_CH + lane];
            float x2 = xw[(size_t)(p2.x & 0xFFFF) * OUT_CH + lane];
            float x3 = xw[(size_t)(p3.x & 0xFFFF) * OUT_CH + lane];
            atomicAdd(&acc[(p0.x >> 16) & (BNODES - 1)][lane], __int_as_float(p0.y) * x0);
            atomicAdd(&acc[(p1.x >> 16) & (BNODES - 1)][lane], __int_as_float(p1.y) * x1);
            atomicAdd(&acc[(p2.x >> 16) & (BNODES - 1)][lane], __int_as_float(p2.y) * x2);
            atomicAdd(&acc[(p3.x >> 16) & (BNODES - 1)][lane], __int_as_float(p3.y) * x3);
        }
    }
    for (; i < myHi; ++i) {
        int2 p0 = epack[i];
        if (ch) {
            float x0 = xw[(size_t)(p0.x & 0xFFFF) * OUT_CH + lane];
            atomicAdd(&acc[(p0.x >> 16) & (BNODES - 1)][lane], __int_as_float(p0.y) * x0);
        }
    }
    __syncthreads();

    // epilogue: bias + log-softmax per node, 16 nodes per wave
    float bv = ch ? bias[lane] : 0.f;
    int node0 = b << BSHIFT;
    for (int n = wid; n < BNODES; n += 4) {
        int node = node0 + n;
        if (node >= N_NODES) break;
        float z = ch ? (acc[n][lane] + bv) : -INFINITY;
        float m = z;
        #pragma unroll
        for (int d = 32; d >= 1; d >>= 1) m = fmaxf(m, __shfl_xor(m, d));
        float e = ch ? expf(z - m) : 0.f;
        float s = e;
        #pragma unroll
        for (int d = 32; d >= 1; d >>= 1) s += __shfl_xor(s, d);
        float lse = m + logf(s);
        if (ch) out[(size_t)node * OUT_CH + lane] = z - lse;
    }
}

extern "C" void kernel_launch(void* const* d_in, const int* in_sizes, int n_in,
                              void* d_out, int out_size, void* d_ws, size_t ws_size,
                              hipStream_t stream) {
    const int*   edge_index = (const int*)d_in[0];
    const float* features   = (const float*)d_in[1];
    const float* eweights   = (const float*)d_in[2];
    const float* weight     = (const float*)d_in[3];
    const float* bias       = (const float*)d_in[4];

    const int* src = edge_index;            // edge_index[0, :]
    const int* dst = edge_index + N_EDGES;  // edge_index[1, :]

    float* out = (float*)d_out;

    // Workspace layout (bytes):
    //   xw      @ 0          : 50000*48*4 = 9,600,000
    //   counts  @ 9,600,000  : NB*4 ~ 3,128
    //   base    @ 9,608,000  : 3,128
    //   cursor  @ 9,616,000  : 3,128
    //   epack   @ 9,624,000  : 12,800,000   (total ~22.4 MB)
    char* ws = (char*)d_ws;
    float* xw     = (float*)(ws + 0);
    int*   counts = (int*)  (ws + 9600000);
    int*   base   = (int*)  (ws + 9608000);
    int*   cursor = (int*)  (ws + 9616000);
    int2*  epack  = (int2*) (ws + 9624000);

    hipMemsetAsync(counts, 0, NB * sizeof(int), stream);

    // 1) xw = features @ weight  (bf16 MFMA)
    gemm_mfma<<<(N_TILES + 3) / 4, 256, 0, stream>>>(features, weight, xw);

    // 2) bucket CSR build (coarse, write-coalesced)
    bucket_hist<<<256, 256, 0, stream>>>(dst, counts);
    bucket_scan<<<1, 1024, 0, stream>>>(counts, base, cursor);
    {
        int nTiles = (N_EDGES + ETILE - 1) / ETILE;
        bin_edges<<<nTiles, 512, 0, stream>>>(src, dst, eweights, cursor, epack);
    }

    // 3) per-bucket aggregate + bias + log-softmax
    bucket_aggregate_lsm<<<NB, 256, 0, stream>>>(base, cursor, epack, xw, bias, out);
}

// Round 6
// 288.718 us; speedup vs baseline: 2.1394x; 2.1394x over previous
//
#include <hip/hip_runtime.h>
#include <math.h>

#define N_NODES 50000
#define N_EDGES 1600000
#define IN_CH   512
#define OUT_CH  48
#define N_TILES (N_NODES / 16)       // 3125 row-tiles, exact

#define BSHIFT  6                    // 64 nodes per bucket
#define BNODES  64
#define NB      ((N_NODES + BNODES - 1) / BNODES)   // 782 buckets
#define ETILE   8192                 // edges per bin_edges block
#define CAP     2816                 // max edges per bucket handled by sort (mean 2046, sigma~45)
#define CHUNK   128                  // edges per wave in seg_aggregate

typedef __attribute__((ext_vector_type(8))) short bf16x8;
typedef __attribute__((ext_vector_type(4))) float f32x4;

// fp32 -> bf16 (round-to-nearest-even), branch-free
static __device__ inline short f2bf(float x) {
    union { float f; unsigned u; } in; in.f = x;
    unsigned r = in.u + 0x7fffu + ((in.u >> 16) & 1u);
    return (short)(r >> 16);
}

// ---------------- Kernel 1: xw = features @ weight via bf16 MFMA ----------------
__global__ __launch_bounds__(256) void gemm_mfma(const float* __restrict__ f,
                                                 const float* __restrict__ w,
                                                 float* __restrict__ xw) {
    __shared__ bf16x8 sB[16 * 3 * 64];   // [s][t][lane], 48 KB

    int tid  = threadIdx.x;
    int lane = tid & 63;
    int wid  = tid >> 6;

    // stage B fragments: w[k][col] -> bf16, frag layout col=lane&15, k=8*(lane>>4)+j
    for (int idx = tid; idx < 16 * 3 * 64 * 8; idx += 256) {
        int j  = idx & 7;
        int ln = (idx >> 3) & 63;
        int st = idx >> 9;           // s*3 + t
        int t  = st % 3;
        int s  = st / 3;
        int k   = s * 32 + ((ln >> 4) << 3) + j;
        int col = t * 16 + (ln & 15);
        reinterpret_cast<short*>(sB)[idx] = f2bf(w[k * OUT_CH + col]);
    }
    __syncthreads();

    int tile = blockIdx.x * 4 + wid;
    if (tile >= N_TILES) return;

    int row = tile * 16 + (lane & 15);
    const float* fp = f + (size_t)row * IN_CH + ((lane >> 4) << 3);

    f32x4 acc0 = {0.f, 0.f, 0.f, 0.f};
    f32x4 acc1 = {0.f, 0.f, 0.f, 0.f};
    f32x4 acc2 = {0.f, 0.f, 0.f, 0.f};

    #pragma unroll 4
    for (int s = 0; s < 16; ++s) {
        float4 a0 = *reinterpret_cast<const float4*>(fp + s * 32);
        float4 a1 = *reinterpret_cast<const float4*>(fp + s * 32 + 4);
        bf16x8 a;
        a[0] = f2bf(a0.x); a[1] = f2bf(a0.y); a[2] = f2bf(a0.z); a[3] = f2bf(a0.w);
        a[4] = f2bf(a1.x); a[5] = f2bf(a1.y); a[6] = f2bf(a1.z); a[7] = f2bf(a1.w);
        bf16x8 b0 = sB[(s * 3 + 0) * 64 + lane];
        bf16x8 b1 = sB[(s * 3 + 1) * 64 + lane];
        bf16x8 b2 = sB[(s * 3 + 2) * 64 + lane];
        acc0 = __builtin_amdgcn_mfma_f32_16x16x32_bf16(a, b0, acc0, 0, 0, 0);
        acc1 = __builtin_amdgcn_mfma_f32_16x16x32_bf16(a, b1, acc1, 0, 0, 0);
        acc2 = __builtin_amdgcn_mfma_f32_16x16x32_bf16(a, b2, acc2, 0, 0, 0);
    }

    float* orow = xw + (size_t)tile * 16 * OUT_CH;
    int c  = lane & 15;
    int r0 = (lane >> 4) * 4;
    #pragma unroll
    for (int r = 0; r < 4; ++r) {
        orow[(size_t)(r0 + r) * OUT_CH +  0 + c] = acc0[r];
        orow[(size_t)(r0 + r) * OUT_CH + 16 + c] = acc1[r];
        orow[(size_t)(r0 + r) * OUT_CH + 32 + c] = acc2[r];
    }
}

// ---------------- Kernel 2: per-bucket histogram (LDS-staged) ----------------
__global__ __launch_bounds__(256) void bucket_hist(const int* __restrict__ dst,
                                                   int* __restrict__ counts) {
    __shared__ int h[NB];
    for (int i = threadIdx.x; i < NB; i += blockDim.x) h[i] = 0;
    __syncthreads();
    for (int e = blockIdx.x * blockDim.x + threadIdx.x; e < N_EDGES;
         e += gridDim.x * blockDim.x)
        atomicAdd(&h[dst[e] >> BSHIFT], 1);
    __syncthreads();
    for (int i = threadIdx.x; i < NB; i += blockDim.x)
        if (h[i]) atomicAdd(&counts[i], h[i]);
}

// ---------------- Kernel 3: exclusive scan over NB buckets (1 block) ----------------
__global__ __launch_bounds__(1024) void bucket_scan(const int* __restrict__ counts,
                                                    int* __restrict__ base,
                                                    int* __restrict__ cursor) {
    __shared__ int sdata[1024];
    int t = threadIdx.x;
    int v = (t < NB) ? counts[t] : 0;
    sdata[t] = v;
    __syncthreads();
    for (int d = 1; d < 1024; d <<= 1) {
        int x = (t >= d) ? sdata[t - d] : 0;
        __syncthreads();
        sdata[t] += x;
        __syncthreads();
    }
    if (t < NB) { int e = sdata[t] - v; base[t] = e; cursor[t] = e; }
}

// ---------------- Kernel 4: LDS-staged binning (coalesced scatter) ----------------
// Packs FULL dst (16 bits) alongside src (16 bits) so downstream kernels know
// the exact destination node.
__global__ __launch_bounds__(512) void bin_edges(const int* __restrict__ src,
                                                 const int* __restrict__ dst,
                                                 const float* __restrict__ ew,
                                                 int* __restrict__ cursor,
                                                 int2* __restrict__ epack) {
    __shared__ int   hist[NB];
    __shared__ int   loff[NB];
    __shared__ int   gbase[NB];
    __shared__ int   ssum[512];
    __shared__ int2  buf[ETILE];      // 64 KB
    __shared__ short bkt[ETILE];      // 16 KB

    int tid = threadIdx.x;
    int tileStart = blockIdx.x * ETILE;
    int tileN = N_EDGES - tileStart; if (tileN > ETILE) tileN = ETILE;

    for (int i = tid; i < NB; i += 512) hist[i] = 0;
    __syncthreads();

    // pass A: ranks via LDS histogram
    int rank[ETILE / 512];
    #pragma unroll
    for (int k = 0; k < ETILE / 512; ++k) {
        int e = tileStart + k * 512 + tid;
        rank[k] = (e < N_EDGES) ? atomicAdd(&hist[dst[e] >> BSHIFT], 1) : 0;
    }
    __syncthreads();

    // reserve global space per bucket
    for (int i = tid; i < NB; i += 512) {
        int c = hist[i];
        gbase[i] = c ? atomicAdd(&cursor[i], c) : 0;
    }

    // exclusive scan of hist -> loff (2 entries per thread)
    int a0 = (2 * tid     < NB) ? hist[2 * tid]     : 0;
    int a1 = (2 * tid + 1 < NB) ? hist[2 * tid + 1] : 0;
    ssum[tid] = a0 + a1;
    __syncthreads();
    for (int d = 1; d < 512; d <<= 1) {
        int x = (tid >= d) ? ssum[tid - d] : 0;
        __syncthreads();
        ssum[tid] += x;
        __syncthreads();
    }
    int excl = ssum[tid] - (a0 + a1);
    if (2 * tid     < NB) loff[2 * tid]     = excl;
    if (2 * tid + 1 < NB) loff[2 * tid + 1] = excl + a0;
    __syncthreads();

    // pass B: stage edges into LDS in bucket order
    #pragma unroll
    for (int k = 0; k < ETILE / 512; ++k) {
        int e = tileStart + k * 512 + tid;
        if (e < N_EDGES) {
            int d = dst[e];
            int b = d >> BSHIFT;
            int slot = loff[b] + rank[k];
            int2 p;
            p.x = (src[e] & 0xFFFF) | (d << 16);   // src 16b | full dst 16b
            p.y = __float_as_int(ew[e]);
            buf[slot] = p;
            bkt[slot] = (short)b;
        }
    }
    __syncthreads();

    // streaming writeout: consecutive slots -> consecutive global positions
    for (int idx = tid; idx < tileN; idx += 512) {
        int b = bkt[idx];
        epack[gbase[b] + idx - loff[b]] = buf[idx];
    }
}

// ---------------- Kernel 5: in-bucket sort by node (finish the radix sort) ----------------
// One block per bucket; 64-counter LDS counting sort; coalesced read & writeback.
__global__ __launch_bounds__(256) void sort_bucket(const int* __restrict__ base,
                                                   const int* __restrict__ cursor,
                                                   int2* __restrict__ epack) {
    __shared__ int2  A[CAP];      // 22.5 KB
    __shared__ int2  B[CAP];      // 22.5 KB
    __shared__ short rk[CAP];     // 5.6 KB
    __shared__ int   hist[BNODES];
    __shared__ int   loff[BNODES];

    int b  = blockIdx.x;
    int lo = base[b], hi = cursor[b];
    int len = hi - lo;
    if (len <= 0 || len > CAP) return;   // oversize: leave unsorted (agg still correct)

    int tid = threadIdx.x;
    if (tid < BNODES) hist[tid] = 0;
    for (int i = tid; i < len; i += 256) A[i] = epack[lo + i];
    __syncthreads();

    for (int i = tid; i < len; i += 256) {
        int key = (((unsigned)A[i].x) >> 16) & (BNODES - 1);
        rk[i] = (short)atomicAdd(&hist[key], 1);
    }
    __syncthreads();

    if (tid < BNODES) {           // wave 0: exclusive scan of 64 counters
        int v = hist[tid];
        int s = v;
        #pragma unroll
        for (int d = 1; d < 64; d <<= 1) {
            int t = __shfl_up(s, d);
            if (tid >= d) s += t;
        }
        loff[tid] = s - v;
    }
    __syncthreads();

    for (int i = tid; i < len; i += 256) {
        int key = (((unsigned)A[i].x) >> 16) & (BNODES - 1);
        B[loff[key] + rk[i]] = A[i];
    }
    __syncthreads();

    for (int i = tid; i < len; i += 256) epack[lo + i] = B[i];
}

// ---------------- Kernel 6: segmented reduction over sorted edges ----------------
// One wave per CHUNK edges; lane = channel. Register-accumulate runs of equal
// node; flush with global fp32 atomicAdd only at run boundaries.
__global__ __launch_bounds__(256) void seg_aggregate(const int2* __restrict__ epack,
                                                     const float* __restrict__ xw,
                                                     float* __restrict__ out) {
    int wv   = (blockIdx.x * blockDim.x + threadIdx.x) >> 6;
    int lane = threadIdx.x & 63;
    int base = wv * CHUNK;
    if (base >= N_EDGES) return;
    int end = base + CHUNK; if (end > N_EDGES) end = N_EDGES;
    bool ch = (lane < OUT_CH);

    int2 q = epack[base];
    float acc = 0.f;
    int cur = ((unsigned)q.x) >> 16;

    for (int i = base; i < end; ++i) {
        int2 qn = (i + 1 < end) ? epack[i + 1] : q;              // prefetch next
        float x = ch ? xw[(size_t)(q.x & 0xFFFF) * OUT_CH + lane] : 0.f;
        int node = ((unsigned)q.x) >> 16;
        if (node != cur) {                                        // wave-uniform branch
            if (ch) atomicAdd(&out[(size_t)cur * OUT_CH + lane], acc);
            acc = 0.f; cur = node;
        }
        acc = fmaf(__int_as_float(q.y), x, acc);
        q = qn;
    }
    if (ch) atomicAdd(&out[(size_t)cur * OUT_CH + lane], acc);
}

// ---------------- Kernel 7: bias + log-softmax, in place, wave per node ----------------
__global__ __launch_bounds__(256) void lsm_rows(float* __restrict__ z,
                                                const float* __restrict__ bias) {
    int node = (blockIdx.x * blockDim.x + threadIdx.x) >> 6;
    int lane = threadIdx.x & 63;
    if (node >= N_NODES) return;
    bool ch = (lane < OUT_CH);

    float v = ch ? (z[(size_t)node * OUT_CH + lane] + bias[lane]) : -INFINITY;
    float m = v;
    #pragma unroll
    for (int d = 32; d >= 1; d >>= 1) m = fmaxf(m, __shfl_xor(m, d));
    float e = ch ? expf(v - m) : 0.f;
    float s = e;
    #pragma unroll
    for (int d = 32; d >= 1; d >>= 1) s += __shfl_xor(s, d);
    float lse = m + logf(s);
    if (ch) z[(size_t)node * OUT_CH + lane] = v - lse;
}

extern "C" void kernel_launch(void* const* d_in, const int* in_sizes, int n_in,
                              void* d_out, int out_size, void* d_ws, size_t ws_size,
                              hipStream_t stream) {
    const int*   edge_index = (const int*)d_in[0];
    const float* features   = (const float*)d_in[1];
    const float* eweights   = (const float*)d_in[2];
    const float* weight     = (const float*)d_in[3];
    const float* bias       = (const float*)d_in[4];

    const int* src = edge_index;            // edge_index[0, :]
    const int* dst = edge_index + N_EDGES;  // edge_index[1, :]

    float* out = (float*)d_out;

    // Workspace layout (bytes):
    //   xw      @ 0          : 50000*48*4 = 9,600,000
    //   counts  @ 9,600,000  : NB*4
    //   base    @ 9,608,000  : NB*4
    //   cursor  @ 9,616,000  : NB*4
    //   epack   @ 9,624,000  : 12,800,000
    char* ws = (char*)d_ws;
    float* xw     = (float*)(ws + 0);
    int*   counts = (int*)  (ws + 9600000);
    int*   base   = (int*)  (ws + 9608000);
    int*   cursor = (int*)  (ws + 9616000);
    int2*  epack  = (int2*) (ws + 9624000);

    hipMemsetAsync(counts, 0, NB * sizeof(int), stream);
    hipMemsetAsync(d_out, 0, (size_t)N_NODES * OUT_CH * sizeof(float), stream);

    // 1) xw = features @ weight  (bf16 MFMA)
    gemm_mfma<<<(N_TILES + 3) / 4, 256, 0, stream>>>(features, weight, xw);

    // 2) bucket binning (coarse, write-coalesced) + in-bucket sort
    bucket_hist<<<256, 256, 0, stream>>>(dst, counts);
    bucket_scan<<<1, 1024, 0, stream>>>(counts, base, cursor);
    bin_edges<<<(N_EDGES + ETILE - 1) / ETILE, 512, 0, stream>>>(src, dst, eweights,
                                                                 cursor, epack);
    sort_bucket<<<NB, 256, 0, stream>>>(base, cursor, epack);

    // 3) segmented reduction (wave per 128-edge chunk)
    {
        int nWaves  = (N_EDGES + CHUNK - 1) / CHUNK;   // 12500
        int nBlocks = (nWaves + 3) / 4;
        seg_aggregate<<<nBlocks, 256, 0, stream>>>(epack, xw, out);
    }
    // 4) bias + log-softmax
    lsm_rows<<<(N_NODES + 3) / 4, 256, 0, stream>>>(out, bias);
}

// Round 7
// 166.217 us; speedup vs baseline: 3.7161x; 1.7370x over previous
//
#include <hip/hip_runtime.h>
#include <math.h>

#define N_NODES 50000
#define N_EDGES 1600000
#define IN_CH   512
#define OUT_CH  48
#define N_TILES (N_NODES / 16)       // 3125 row-tiles, exact

#define BSHIFT  6                    // 64 nodes per bucket
#define BNODES  64
#define NB      ((N_NODES + BNODES - 1) / BNODES)   // 782 buckets
#define ETILE   8192                 // edges per bin_edges block
#define CAP     2816                 // max edges per bucket handled by sort (mean 2046, sigma~45)
#define CHUNK   128                  // edges per wave in seg_aggregate (divides N_EDGES exactly)

typedef __attribute__((ext_vector_type(8))) short bf16x8;
typedef __attribute__((ext_vector_type(4))) float f32x4;

// fp32 -> bf16 (round-to-nearest-even), branch-free
static __device__ inline short f2bf(float x) {
    union { float f; unsigned u; } in; in.f = x;
    unsigned r = in.u + 0x7fffu + ((in.u >> 16) & 1u);
    return (short)(r >> 16);
}

// ---------------- Kernel 1: xw = features @ weight via bf16 MFMA ----------------
__global__ __launch_bounds__(256) void gemm_mfma(const float* __restrict__ f,
                                                 const float* __restrict__ w,
                                                 float* __restrict__ xw) {
    __shared__ bf16x8 sB[16 * 3 * 64];   // [s][t][lane], 48 KB

    int tid  = threadIdx.x;
    int lane = tid & 63;
    int wid  = tid >> 6;

    // stage B fragments: w[k][col] -> bf16, frag layout col=lane&15, k=8*(lane>>4)+j
    for (int idx = tid; idx < 16 * 3 * 64 * 8; idx += 256) {
        int j  = idx & 7;
        int ln = (idx >> 3) & 63;
        int st = idx >> 9;           // s*3 + t
        int t  = st % 3;
        int s  = st / 3;
        int k   = s * 32 + ((ln >> 4) << 3) + j;
        int col = t * 16 + (ln & 15);
        reinterpret_cast<short*>(sB)[idx] = f2bf(w[k * OUT_CH + col]);
    }
    __syncthreads();

    int tile = blockIdx.x * 4 + wid;
    if (tile >= N_TILES) return;

    int row = tile * 16 + (lane & 15);
    const float* fp = f + (size_t)row * IN_CH + ((lane >> 4) << 3);

    f32x4 acc0 = {0.f, 0.f, 0.f, 0.f};
    f32x4 acc1 = {0.f, 0.f, 0.f, 0.f};
    f32x4 acc2 = {0.f, 0.f, 0.f, 0.f};

    #pragma unroll 4
    for (int s = 0; s < 16; ++s) {
        float4 a0 = *reinterpret_cast<const float4*>(fp + s * 32);
        float4 a1 = *reinterpret_cast<const float4*>(fp + s * 32 + 4);
        bf16x8 a;
        a[0] = f2bf(a0.x); a[1] = f2bf(a0.y); a[2] = f2bf(a0.z); a[3] = f2bf(a0.w);
        a[4] = f2bf(a1.x); a[5] = f2bf(a1.y); a[6] = f2bf(a1.z); a[7] = f2bf(a1.w);
        bf16x8 b0 = sB[(s * 3 + 0) * 64 + lane];
        bf16x8 b1 = sB[(s * 3 + 1) * 64 + lane];
        bf16x8 b2 = sB[(s * 3 + 2) * 64 + lane];
        acc0 = __builtin_amdgcn_mfma_f32_16x16x32_bf16(a, b0, acc0, 0, 0, 0);
        acc1 = __builtin_amdgcn_mfma_f32_16x16x32_bf16(a, b1, acc1, 0, 0, 0);
        acc2 = __builtin_amdgcn_mfma_f32_16x16x32_bf16(a, b2, acc2, 0, 0, 0);
    }

    float* orow = xw + (size_t)tile * 16 * OUT_CH;
    int c  = lane & 15;
    int r0 = (lane >> 4) * 4;
    #pragma unroll
    for (int r = 0; r < 4; ++r) {
        orow[(size_t)(r0 + r) * OUT_CH +  0 + c] = acc0[r];
        orow[(size_t)(r0 + r) * OUT_CH + 16 + c] = acc1[r];
        orow[(size_t)(r0 + r) * OUT_CH + 32 + c] = acc2[r];
    }
}

// ---------------- Kernel 2: per-bucket histogram (LDS-staged) ----------------
__global__ __launch_bounds__(256) void bucket_hist(const int* __restrict__ dst,
                                                   int* __restrict__ counts) {
    __shared__ int h[NB];
    for (int i = threadIdx.x; i < NB; i += blockDim.x) h[i] = 0;
    __syncthreads();
    for (int e = blockIdx.x * blockDim.x + threadIdx.x; e < N_EDGES;
         e += gridDim.x * blockDim.x)
        atomicAdd(&h[dst[e] >> BSHIFT], 1);
    __syncthreads();
    for (int i = threadIdx.x; i < NB; i += blockDim.x)
        if (h[i]) atomicAdd(&counts[i], h[i]);
}

// ---------------- Kernel 3: exclusive scan over NB buckets (1 block) ----------------
__global__ __launch_bounds__(1024) void bucket_scan(const int* __restrict__ counts,
                                                    int* __restrict__ base,
                                                    int* __restrict__ cursor) {
    __shared__ int sdata[1024];
    int t = threadIdx.x;
    int v = (t < NB) ? counts[t] : 0;
    sdata[t] = v;
    __syncthreads();
    for (int d = 1; d < 1024; d <<= 1) {
        int x = (t >= d) ? sdata[t - d] : 0;
        __syncthreads();
        sdata[t] += x;
        __syncthreads();
    }
    if (t < NB) { int e = sdata[t] - v; base[t] = e; cursor[t] = e; }
}

// ---------------- Kernel 4: LDS-staged binning (coalesced scatter) ----------------
__global__ __launch_bounds__(512) void bin_edges(const int* __restrict__ src,
                                                 const int* __restrict__ dst,
                                                 const float* __restrict__ ew,
                                                 int* __restrict__ cursor,
                                                 int2* __restrict__ epack) {
    __shared__ int   hist[NB];
    __shared__ int   loff[NB];
    __shared__ int   gbase[NB];
    __shared__ int   ssum[512];
    __shared__ int2  buf[ETILE];      // 64 KB
    __shared__ short bkt[ETILE];      // 16 KB

    int tid = threadIdx.x;
    int tileStart = blockIdx.x * ETILE;
    int tileN = N_EDGES - tileStart; if (tileN > ETILE) tileN = ETILE;

    for (int i = tid; i < NB; i += 512) hist[i] = 0;
    __syncthreads();

    // pass A: ranks via LDS histogram
    int rank[ETILE / 512];
    #pragma unroll
    for (int k = 0; k < ETILE / 512; ++k) {
        int e = tileStart + k * 512 + tid;
        rank[k] = (e < N_EDGES) ? atomicAdd(&hist[dst[e] >> BSHIFT], 1) : 0;
    }
    __syncthreads();

    // reserve global space per bucket
    for (int i = tid; i < NB; i += 512) {
        int c = hist[i];
        gbase[i] = c ? atomicAdd(&cursor[i], c) : 0;
    }

    // exclusive scan of hist -> loff (2 entries per thread)
    int a0 = (2 * tid     < NB) ? hist[2 * tid]     : 0;
    int a1 = (2 * tid + 1 < NB) ? hist[2 * tid + 1] : 0;
    ssum[tid] = a0 + a1;
    __syncthreads();
    for (int d = 1; d < 512; d <<= 1) {
        int x = (tid >= d) ? ssum[tid - d] : 0;
        __syncthreads();
        ssum[tid] += x;
        __syncthreads();
    }
    int excl = ssum[tid] - (a0 + a1);
    if (2 * tid     < NB) loff[2 * tid]     = excl;
    if (2 * tid + 1 < NB) loff[2 * tid + 1] = excl + a0;
    __syncthreads();

    // pass B: stage edges into LDS in bucket order
    #pragma unroll
    for (int k = 0; k < ETILE / 512; ++k) {
        int e = tileStart + k * 512 + tid;
        if (e < N_EDGES) {
            int d = dst[e];
            int b = d >> BSHIFT;
            int slot = loff[b] + rank[k];
            int2 p;
            p.x = (src[e] & 0xFFFF) | (d << 16);   // src 16b | full dst 16b
            p.y = __float_as_int(ew[e]);
            buf[slot] = p;
            bkt[slot] = (short)b;
        }
    }
    __syncthreads();

    // streaming writeout: consecutive slots -> consecutive global positions
    for (int idx = tid; idx < tileN; idx += 512) {
        int b = bkt[idx];
        epack[gbase[b] + idx - loff[b]] = buf[idx];
    }
}

// ---------------- Kernel 5: in-bucket sort by node (finish the radix sort) ----------------
__global__ __launch_bounds__(256) void sort_bucket(const int* __restrict__ base,
                                                   const int* __restrict__ cursor,
                                                   int2* __restrict__ epack) {
    __shared__ int2  A[CAP];      // 22.5 KB
    __shared__ int2  B[CAP];      // 22.5 KB
    __shared__ short rk[CAP];     // 5.6 KB
    __shared__ int   hist[BNODES];
    __shared__ int   loff[BNODES];

    int b  = blockIdx.x;
    int lo = base[b], hi = cursor[b];
    int len = hi - lo;
    if (len <= 0 || len > CAP) return;   // oversize: leave unsorted (agg still correct)

    int tid = threadIdx.x;
    if (tid < BNODES) hist[tid] = 0;
    for (int i = tid; i < len; i += 256) A[i] = epack[lo + i];
    __syncthreads();

    for (int i = tid; i < len; i += 256) {
        int key = (((unsigned)A[i].x) >> 16) & (BNODES - 1);
        rk[i] = (short)atomicAdd(&hist[key], 1);
    }
    __syncthreads();

    if (tid < BNODES) {           // wave 0: exclusive scan of 64 counters
        int v = hist[tid];
        int s = v;
        #pragma unroll
        for (int d = 1; d < 64; d <<= 1) {
            int t = __shfl_up(s, d);
            if (tid >= d) s += t;
        }
        loff[tid] = s - v;
    }
    __syncthreads();

    for (int i = tid; i < len; i += 256) {
        int key = (((unsigned)A[i].x) >> 16) & (BNODES - 1);
        B[loff[key] + rk[i]] = A[i];
    }
    __syncthreads();

    for (int i = tid; i < len; i += 256) epack[lo + i] = B[i];
}

// ---------------- Kernel 6: segmented reduction over sorted edges ----------------
// One wave per 128-edge chunk. Edges lane-held (2 coalesced int2 loads), then
// 8x-unrolled inner loop: 8 register shfl-broadcasts -> 8 INDEPENDENT xw
// gathers in flight -> 8 FMAs with rare run-boundary atomic flush.
__global__ __launch_bounds__(256) void seg_aggregate(const int2* __restrict__ epack,
                                                     const float* __restrict__ xw,
                                                     float* __restrict__ out) {
    int wv   = (blockIdx.x * blockDim.x + threadIdx.x) >> 6;
    int lane = threadIdx.x & 63;
    int base = wv * CHUNK;
    if (base >= N_EDGES) return;          // CHUNK divides N_EDGES exactly
    bool ch = (lane < OUT_CH);

    // lane-held edges: 128 edges across 64 lanes
    int2 e0 = epack[base + lane];
    int2 e1 = epack[base + 64 + lane];

    float acc = 0.f;
    int cur = ((unsigned)__shfl(e0.x, 0)) >> 16;

    #pragma unroll
    for (int j = 0; j < CHUNK; j += 8) {
        int px[8], pw[8];
        #pragma unroll
        for (int k = 0; k < 8; ++k) {
            int jj = j + k;                        // compile-time
            int sx = (jj < 64) ? e0.x : e1.x;
            int sy = (jj < 64) ? e0.y : e1.y;
            px[k] = __shfl(sx, jj & 63);
            pw[k] = __shfl(sy, jj & 63);
        }
        float x[8];
        #pragma unroll
        for (int k = 0; k < 8; ++k)
            x[k] = ch ? xw[(size_t)(px[k] & 0xFFFF) * OUT_CH + lane] : 0.f;
        #pragma unroll
        for (int k = 0; k < 8; ++k) {
            int node = ((unsigned)px[k]) >> 16;
            if (node != cur) {                     // wave-uniform
                if (ch) atomicAdd(&out[(size_t)cur * OUT_CH + lane], acc);
                acc = 0.f; cur = node;
            }
            acc = fmaf(__int_as_float(pw[k]), x[k], acc);
        }
    }
    if (ch) atomicAdd(&out[(size_t)cur * OUT_CH + lane], acc);
}

// ---------------- Kernel 7: bias + log-softmax, in place, wave per node ----------------
__global__ __launch_bounds__(256) void lsm_rows(float* __restrict__ z,
                                                const float* __restrict__ bias) {
    int node = (blockIdx.x * blockDim.x + threadIdx.x) >> 6;
    int lane = threadIdx.x & 63;
    if (node >= N_NODES) return;
    bool ch = (lane < OUT_CH);

    float v = ch ? (z[(size_t)node * OUT_CH + lane] + bias[lane]) : -INFINITY;
    float m = v;
    #pragma unroll
    for (int d = 32; d >= 1; d >>= 1) m = fmaxf(m, __shfl_xor(m, d));
    float e = ch ? expf(v - m) : 0.f;
    float s = e;
    #pragma unroll
    for (int d = 32; d >= 1; d >>= 1) s += __shfl_xor(s, d);
    float lse = m + logf(s);
    if (ch) z[(size_t)node * OUT_CH + lane] = v - lse;
}

extern "C" void kernel_launch(void* const* d_in, const int* in_sizes, int n_in,
                              void* d_out, int out_size, void* d_ws, size_t ws_size,
                              hipStream_t stream) {
    const int*   edge_index = (const int*)d_in[0];
    const float* features   = (const float*)d_in[1];
    const float* eweights   = (const float*)d_in[2];
    const float* weight     = (const float*)d_in[3];
    const float* bias       = (const float*)d_in[4];

    const int* src = edge_index;            // edge_index[0, :]
    const int* dst = edge_index + N_EDGES;  // edge_index[1, :]

    float* out = (float*)d_out;

    char* ws = (char*)d_ws;
    float* xw     = (float*)(ws + 0);
    int*   counts = (int*)  (ws + 9600000);
    int*   base   = (int*)  (ws + 9608000);
    int*   cursor = (int*)  (ws + 9616000);
    int2*  epack  = (int2*) (ws + 9624000);

    hipMemsetAsync(counts, 0, NB * sizeof(int), stream);
    hipMemsetAsync(d_out, 0, (size_t)N_NODES * OUT_CH * sizeof(float), stream);

    // 1) xw = features @ weight  (bf16 MFMA)
    gemm_mfma<<<(N_TILES + 3) / 4, 256, 0, stream>>>(features, weight, xw);

    // 2) bucket binning (coarse, write-coalesced) + in-bucket sort
    bucket_hist<<<256, 256, 0, stream>>>(dst, counts);
    bucket_scan<<<1, 1024, 0, stream>>>(counts, base, cursor);
    bin_edges<<<(N_EDGES + ETILE - 1) / ETILE, 512, 0, stream>>>(src, dst, eweights,
                                                                 cursor, epack);
    sort_bucket<<<NB, 256, 0, stream>>>(base, cursor, epack);

    // 3) segmented reduction (wave per 128-edge chunk, 8-deep gather ILP)
    {
        int nWaves  = (N_EDGES + CHUNK - 1) / CHUNK;   // 12500
        int nBlocks = (nWaves + 3) / 4;
        seg_aggregate<<<nBlocks, 256, 0, stream>>>(epack, xw, out);
    }
    // 4) bias + log-softmax
    lsm_rows<<<(N_NODES + 3) / 4, 256, 0, stream>>>(out, bias);
}